// Round 2
// baseline (587.647 us; speedup 1.0000x reference)
//
#include <hip/hip_runtime.h>

// B=128, C_IN=128, C_HID=256, C_OUT=128, H*W=1600, E=8, TOP_K=2.
#define CIN   128
#define CHID  256
#define COUT  128
#define HWPX  1600
#define PXT   64          // pixels per block tile (16 per wave)
#define NPXT  25          // 1600 / 64

typedef __attribute__((ext_vector_type(8))) short bf16x8;  // 8 bf16 = 4 VGPRs
typedef __attribute__((ext_vector_type(4))) float f32x4;   // MFMA C/D

__device__ __forceinline__ unsigned short f2bf(float f) {
  // round-to-nearest-even fp32 -> bf16
  unsigned int u = __builtin_bit_cast(unsigned int, f);
  u += 0x7FFFu + ((u >> 16) & 1u);
  return (unsigned short)(u >> 16);
}

__device__ __forceinline__ float silu_f(float v) {
  return v / (1.0f + __expf(-v));
}

// Convert weights fp32->bf16. W1 additionally gets a ROW PERMUTATION so that
// GEMM1's MFMA D-layout (lane q holds ch = q*4+r per 16-row tile) lands the
// hidden activations directly in GEMM2's B-fragment order (lane q needs
// ch = q*8+j). Per 32-ch group: position p = mt*16 + row  holds true channel
// ch = (row>>2)*8 + (row&3) + mt*4.
__global__ __launch_bounds__(256) void convert_w_kernel(
    const float* __restrict__ W1, const float* __restrict__ W2,
    unsigned short* __restrict__ W1b, unsigned short* __restrict__ W2b) {
  int i = blockIdx.x * 256 + threadIdx.x;  // covers 8*256*128
  W2b[i] = f2bf(W2[i]);
  int c = i % CIN;
  int p = (i / CIN) % CHID;
  int e = i / (CIN * CHID);
  int g  = p >> 5;
  int pp = p & 31;
  int mt = pp >> 4;
  int row = pp & 15;
  int ch = (g << 5) + ((row >> 2) << 3) + (row & 3) + (mt << 2);
  W1b[i] = f2bf(W1[(e * CHID + ch) * CIN + c]);
}

__global__ __launch_bounds__(256) void moe_kernel(
    const float* __restrict__ x, const float* __restrict__ wts,
    const int* __restrict__ idx, const unsigned short* __restrict__ W1,
    const float* __restrict__ b1, const unsigned short* __restrict__ W2,
    const float* __restrict__ b2, float* __restrict__ out) {
  // x tile, bf16, [px][cin]; +8 pad keeps rows 16B-aligned for ds_read_b128.
  // Only LDS use in the kernel; single barrier.
  __shared__ unsigned short xs[PXT][CIN + 8];

  const int tid  = threadIdx.x;
  const int wave = tid >> 6;
  const int lane = tid & 63;
  const int q    = lane >> 4;   // quad 0..3
  const int r16  = lane & 15;   // 0..15

  const int blk = blockIdx.x;
  const int b   = blk / NPXT;
  const int pt  = blk - b * NPXT;
  const int px0 = pt * PXT;

  // ---- stage x tile: coalesced scalar fp32 loads (64 consecutive px/wave),
  //      pack 8 cin as bf16x8, one ds_write_b128 per 8 values.
  {
    const float* xb = x + (long)b * CIN * HWPX + px0;
    const int pxl = tid & 63;        // pixel this thread owns
    const int cb  = tid >> 6;        // cin block 0..3
#pragma unroll
    for (int i = 0; i < 4; ++i) {
      const int cin0 = cb * 32 + i * 8;
      bf16x8 v;
#pragma unroll
      for (int j = 0; j < 8; ++j)
        v[j] = (short)f2bf(xb[(cin0 + j) * HWPX + pxl]);
      *reinterpret_cast<bf16x8*>(&xs[pxl][cin0]) = v;
    }
  }
  __syncthreads();

  // ---- B-fragments of x for this wave's 16 px: read ONCE, pinned in regs.
  bf16x8 xfrag[4];
#pragma unroll
  for (int ks = 0; ks < 4; ++ks)
    xfrag[ks] = *reinterpret_cast<const bf16x8*>(&xs[wave * 16 + r16][ks * 32 + q * 8]);

  f32x4 accO[8];
#pragma unroll
  for (int mt = 0; mt < 8; ++mt) accO[mt] = (f32x4){0.f, 0.f, 0.f, 0.f};

  const int   e0 = idx[b * 2 + 0], e1 = idx[b * 2 + 1];
  const float g0 = wts[b * 2 + 0], g1 = wts[b * 2 + 1];

  for (int slot = 0; slot < 2; ++slot) {
    const int   e = slot ? e1 : e0;
    const float g = slot ? g1 : g0;
    const unsigned short* W1e = W1 + (long)e * CHID * CIN;   // row-permuted
    const unsigned short* W2e = W2 + (long)e * COUT * CHID;
    const float* b1e = b1 + e * CHID;

    for (int grp = 0; grp < 8; ++grp) {   // 32 hidden ch per group
      const int base = grp * 32;

      // GEMM1: two 16-row m-tiles of (permuted) W1, K = CIN = 128
      f32x4 aA = (f32x4){0.f, 0.f, 0.f, 0.f};
      f32x4 aB = (f32x4){0.f, 0.f, 0.f, 0.f};
#pragma unroll
      for (int ks = 0; ks < 4; ++ks) {
        const bf16x8 w0 = *reinterpret_cast<const bf16x8*>(
            W1e + (base + r16) * CIN + ks * 32 + q * 8);
        const bf16x8 w1 = *reinterpret_cast<const bf16x8*>(
            W1e + (base + 16 + r16) * CIN + ks * 32 + q * 8);
        aA = __builtin_amdgcn_mfma_f32_16x16x32_bf16(w0, xfrag[ks], aA, 0, 0, 0);
        aB = __builtin_amdgcn_mfma_f32_16x16x32_bf16(w1, xfrag[ks], aB, 0, 0, 0);
      }

      // bias + SiLU + gate, pack into GEMM2 B-fragment (ch = base + q*8 + j)
      const f32x4 bA = *reinterpret_cast<const f32x4*>(&b1e[base + q * 8]);
      const f32x4 bB = *reinterpret_cast<const f32x4*>(&b1e[base + q * 8 + 4]);
      bf16x8 h;
#pragma unroll
      for (int j = 0; j < 4; ++j) {
        h[j]     = (short)f2bf(g * silu_f(aA[j] + bA[j]));
        h[4 + j] = (short)f2bf(g * silu_f(aB[j] + bB[j]));
      }

      // GEMM2 partial-K (this 32-ch chunk), both slots chain into accO
#pragma unroll
      for (int mt = 0; mt < 8; ++mt) {
        const bf16x8 w2 = *reinterpret_cast<const bf16x8*>(
            W2e + (mt * 16 + r16) * CHID + base + q * 8);
        accO[mt] = __builtin_amdgcn_mfma_f32_16x16x32_bf16(w2, h, accO[mt], 0, 0, 0);
      }
    }
  }

  // ---- epilogue: + g0*b2[e0] + g1*b2[e1], store out[b][co][px]
  const float* b2e0 = b2 + e0 * COUT;
  const float* b2e1 = b2 + e1 * COUT;
  const long ob = (long)b * COUT * HWPX + px0 + wave * 16 + r16;
#pragma unroll
  for (int mt = 0; mt < 8; ++mt) {
    const int co = mt * 16 + q * 4;
    const f32x4 v = accO[mt] +
                    g0 * (*reinterpret_cast<const f32x4*>(&b2e0[co])) +
                    g1 * (*reinterpret_cast<const f32x4*>(&b2e1[co]));
#pragma unroll
    for (int r = 0; r < 4; ++r)
      out[ob + (long)(co + r) * HWPX] = v[r];
  }
}

extern "C" void kernel_launch(void* const* d_in, const int* in_sizes, int n_in,
                              void* d_out, int out_size, void* d_ws, size_t ws_size,
                              hipStream_t stream) {
  const float* x   = (const float*)d_in[0];
  const float* wts = (const float*)d_in[1];
  const int*   idx = (const int*)d_in[2];
  const float* W1  = (const float*)d_in[3];
  const float* b1  = (const float*)d_in[4];
  const float* W2  = (const float*)d_in[5];
  const float* b2  = (const float*)d_in[6];
  float* out = (float*)d_out;

  unsigned short* W1b = (unsigned short*)d_ws;                    // 8*256*128
  unsigned short* W2b = (unsigned short*)d_ws + (8 * CHID * CIN); // 8*128*256

  convert_w_kernel<<<262144 / 256, 256, 0, stream>>>(W1, W2, W1b, W2b);
  moe_kernel<<<128 * NPXT, 256, 0, stream>>>(x, wts, idx, W1b, b1, W2b, b2, out);
}

// Round 4
// 338.067 us; speedup vs baseline: 1.7383x; 1.7383x over previous
//
#include <hip/hip_runtime.h>

// B=128, C_IN=128, C_HID=256, C_OUT=128, H*W=1600, E=8, TOP_K=2.
#define CIN   128
#define CHID  256
#define COUT  128
#define HWPX  1600
#define PXW   64          // pixels per wave (= per block); 4 MFMA n-tiles
#define NPXT  25          // 1600 / 64

typedef __attribute__((ext_vector_type(8))) short bf16x8;  // 8 bf16 = 4 VGPRs
typedef __attribute__((ext_vector_type(4))) float f32x4;   // MFMA C/D

__device__ __forceinline__ unsigned short f2bf(float f) {
  // round-to-nearest-even fp32 -> bf16
  unsigned int u = __builtin_bit_cast(unsigned int, f);
  u += 0x7FFFu + ((u >> 16) & 1u);
  return (unsigned short)(u >> 16);
}

__device__ __forceinline__ unsigned int pack_bf2(float a, float b) {
  return (unsigned int)f2bf(a) | ((unsigned int)f2bf(b) << 16);
}

// packed: bf16(lo=a, hi=b) with gate*silu applied
__device__ __forceinline__ unsigned int silu_gate_pk(float a, float b, float g) {
  const float sa = g * a / (1.0f + __expf(-a));
  const float sb = g * b / (1.0f + __expf(-b));
  return pack_bf2(sa, sb);
}

// fp32->bf16 weight convert. W1 gets the ROW PERMUTATION that makes GEMM1's
// MFMA D-layout land hidden activations directly in GEMM2's B-fragment order:
// per 32-ch group, position p = mt*16 + row holds true ch = (row>>2)*8 + (row&3) + mt*4.
__global__ __launch_bounds__(256) void convert_w_kernel(
    const float* __restrict__ W1, const float* __restrict__ W2,
    unsigned short* __restrict__ W1b, unsigned short* __restrict__ W2b) {
  int i = blockIdx.x * 256 + threadIdx.x;  // covers 8*256*128
  W2b[i] = f2bf(W2[i]);
  int c = i % CIN;
  int p = (i / CIN) % CHID;
  int e = i / (CIN * CHID);
  int g  = p >> 5;
  int pp = p & 31;
  int mt = pp >> 4;
  int row = pp & 15;
  int ch = (g << 5) + ((row >> 2) << 3) + (row & 3) + (mt << 2);
  W1b[i] = f2bf(W1[(e * CHID + ch) * CIN + c]);
}

__global__ __launch_bounds__(64, 2) void moe_kernel(
    const float* __restrict__ x, const float* __restrict__ wts,
    const int* __restrict__ idx, const unsigned short* __restrict__ W1,
    const float* __restrict__ b1, const unsigned short* __restrict__ W2,
    const float* __restrict__ b2, float* __restrict__ out) {
  // x tile, bf16, [px][cin]; +8 pad (layout measured conflict-free in R2).
  __shared__ unsigned short xs[PXW][CIN + 8];

  const int lane = threadIdx.x;  // one wave per block
  const int q    = lane >> 4;    // quad 0..3
  const int r16  = lane & 15;    // 0..15

  const int blk = blockIdx.x;
  const int b   = blk / NPXT;
  const int pt  = blk - b * NPXT;
  const int px0 = pt * PXW;

  // ---- stage x tile: lane owns px=lane; 128 coalesced scalar fp32 loads,
  //      packed bf16 conversion, 16 ds_write_b128.
  {
    const float* xb = x + (long)b * CIN * HWPX + px0 + lane;
#pragma unroll
    for (int c8 = 0; c8 < 16; ++c8) {
      const int c0 = c8 * 8;
      float v[8];
#pragma unroll
      for (int j = 0; j < 8; ++j) v[j] = xb[(long)(c0 + j) * HWPX];
      union { bf16x8 w; unsigned int u[4]; } t;
#pragma unroll
      for (int d = 0; d < 4; ++d)
        t.u[d] = pack_bf2(v[2 * d], v[2 * d + 1]);
      *reinterpret_cast<bf16x8*>(&xs[lane][c0]) = t.w;
    }
  }
  __syncthreads();

  // ---- pin x B-fragments for ks=0,1 (ks=2,3 reloaded per group to stay
  //      under the 256-VGPR / 2-waves-per-SIMD cliff).
  bf16x8 xpin[2][4];
#pragma unroll
  for (int ks = 0; ks < 2; ++ks)
#pragma unroll
    for (int nt = 0; nt < 4; ++nt)
      xpin[ks][nt] = *reinterpret_cast<const bf16x8*>(
          &xs[nt * 16 + r16][ks * 32 + q * 8]);

  f32x4 accO[8][4];
#pragma unroll
  for (int mt = 0; mt < 8; ++mt)
#pragma unroll
    for (int nt = 0; nt < 4; ++nt) accO[mt][nt] = (f32x4){0.f, 0.f, 0.f, 0.f};

  const int   e0 = idx[b * 2 + 0], e1 = idx[b * 2 + 1];
  const float g0 = wts[b * 2 + 0], g1 = wts[b * 2 + 1];

  for (int slot = 0; slot < 2; ++slot) {
    const int   e = slot ? e1 : e0;
    const float g = slot ? g1 : g0;
    const unsigned short* W1e = W1 + (long)e * CHID * CIN;   // row-permuted
    const unsigned short* W2e = W2 + (long)e * COUT * CHID;
    const float* b1e = b1 + e * CHID;

    for (int grp = 0; grp < 8; ++grp) {   // 32 hidden ch per group
      const int base = grp * 32;

      // GEMM1: two 16-row m-tiles of (permuted) W1, K=128; each weight
      // fragment feeds 4 MFMAs (4 n-tiles).
      f32x4 aA[4], aB[4];
#pragma unroll
      for (int nt = 0; nt < 4; ++nt) {
        aA[nt] = (f32x4){0.f, 0.f, 0.f, 0.f};
        aB[nt] = (f32x4){0.f, 0.f, 0.f, 0.f};
      }
#pragma unroll
      for (int ks = 0; ks < 4; ++ks) {
        const bf16x8 w0 = *reinterpret_cast<const bf16x8*>(
            W1e + (base + r16) * CIN + ks * 32 + q * 8);
        const bf16x8 w1 = *reinterpret_cast<const bf16x8*>(
            W1e + (base + 16 + r16) * CIN + ks * 32 + q * 8);
        bf16x8 xf[4];
#pragma unroll
        for (int nt = 0; nt < 4; ++nt) {
          if (ks < 2)
            xf[nt] = xpin[ks][nt];
          else
            xf[nt] = *reinterpret_cast<const bf16x8*>(
                &xs[nt * 16 + r16][ks * 32 + q * 8]);
        }
#pragma unroll
        for (int nt = 0; nt < 4; ++nt) {
          aA[nt] = __builtin_amdgcn_mfma_f32_16x16x32_bf16(w0, xf[nt], aA[nt], 0, 0, 0);
          aB[nt] = __builtin_amdgcn_mfma_f32_16x16x32_bf16(w1, xf[nt], aB[nt], 0, 0, 0);
        }
      }

      // bias + SiLU + gate -> GEMM2 B-fragments (ch = base + q*8 + j)
      const f32x4 bA = *reinterpret_cast<const f32x4*>(&b1e[base + q * 8]);
      const f32x4 bB = *reinterpret_cast<const f32x4*>(&b1e[base + q * 8 + 4]);
      union { bf16x8 v; unsigned int u[4]; } h[4];
#pragma unroll
      for (int nt = 0; nt < 4; ++nt) {
        h[nt].u[0] = silu_gate_pk(aA[nt][0] + bA[0], aA[nt][1] + bA[1], g);
        h[nt].u[1] = silu_gate_pk(aA[nt][2] + bA[2], aA[nt][3] + bA[3], g);
        h[nt].u[2] = silu_gate_pk(aB[nt][0] + bB[0], aB[nt][1] + bB[1], g);
        h[nt].u[3] = silu_gate_pk(aB[nt][2] + bB[2], aB[nt][3] + bB[3], g);
      }

      // GEMM2 partial-K (this 32-ch chunk); each W2 fragment feeds 4 MFMAs.
#pragma unroll
      for (int mt = 0; mt < 8; ++mt) {
        const bf16x8 w2 = *reinterpret_cast<const bf16x8*>(
            W2e + (mt * 16 + r16) * CHID + base + q * 8);
#pragma unroll
        for (int nt = 0; nt < 4; ++nt)
          accO[mt][nt] = __builtin_amdgcn_mfma_f32_16x16x32_bf16(w2, h[nt].v, accO[mt][nt], 0, 0, 0);
      }
    }
  }

  // ---- epilogue: + g0*b2[e0] + g1*b2[e1], store out[b][co][px]
  const float* b2e0 = b2 + e0 * COUT;
  const float* b2e1 = b2 + e1 * COUT;
  const long ob = (long)b * COUT * HWPX + px0 + r16;
#pragma unroll
  for (int mt = 0; mt < 8; ++mt) {
    const int co = mt * 16 + q * 4;
    const f32x4 bias = g0 * (*reinterpret_cast<const f32x4*>(&b2e0[co])) +
                       g1 * (*reinterpret_cast<const f32x4*>(&b2e1[co]));
#pragma unroll
    for (int nt = 0; nt < 4; ++nt) {
      const f32x4 v = accO[mt][nt] + bias;
#pragma unroll
      for (int r = 0; r < 4; ++r)
        out[ob + (long)(co + r) * HWPX + nt * 16] = v[r];
    }
  }
}

extern "C" void kernel_launch(void* const* d_in, const int* in_sizes, int n_in,
                              void* d_out, int out_size, void* d_ws, size_t ws_size,
                              hipStream_t stream) {
  const float* x   = (const float*)d_in[0];
  const float* wts = (const float*)d_in[1];
  const int*   idx = (const int*)d_in[2];
  const float* W1  = (const float*)d_in[3];
  const float* b1  = (const float*)d_in[4];
  const float* W2  = (const float*)d_in[5];
  const float* b2  = (const float*)d_in[6];
  float* out = (float*)d_out;

  unsigned short* W1b = (unsigned short*)d_ws;                    // 8*256*128
  unsigned short* W2b = (unsigned short*)d_ws + (8 * CHID * CIN); // 8*128*256

  convert_w_kernel<<<262144 / 256, 256, 0, stream>>>(W1, W2, W1b, W2b);
  moe_kernel<<<128 * NPXT, 64, 0, stream>>>(x, wts, idx, W1b, b1, W2b, b2, out);
}

// Round 5
// 302.844 us; speedup vs baseline: 1.9404x; 1.1163x over previous
//
#include <hip/hip_runtime.h>

// B=128, C_IN=128, C_HID=256, C_OUT=128, H*W=1600, E=8, TOP_K=2.
#define CIN   128
#define CHID  256
#define COUT  128
#define HWPX  1600

typedef __attribute__((ext_vector_type(8))) short bf16x8;  // 8 bf16 = 4 VGPRs
typedef __attribute__((ext_vector_type(4))) float f32x4;   // MFMA C/D

__device__ __forceinline__ unsigned short f2bf(float f) {
  // round-to-nearest-even fp32 -> bf16
  unsigned int u = __builtin_bit_cast(unsigned int, f);
  u += 0x7FFFu + ((u >> 16) & 1u);
  return (unsigned short)(u >> 16);
}
__device__ __forceinline__ unsigned int pack_bf2(float a, float b) {
  return (unsigned int)f2bf(a) | ((unsigned int)f2bf(b) << 16);
}
__device__ __forceinline__ unsigned int silu_gate_pk(float a, float b, float g) {
  const float sa = g * a / (1.0f + __expf(-a));
  const float sb = g * b / (1.0f + __expf(-b));
  return pack_bf2(sa, sb);
}

// fp32->bf16 convert into LDS-slice-ordered, swizzled layouts.
// W1b: [e][grp][512 chunks][8], chunk pos p = r*16 + ((c + r) & 15), where
//   r = GEMM row-position in the 32-row slice (h-trick permuted:
//   position mt*16+row holds true ch = (row>>2)*8 + (row&3) + mt*4),
//   c = cin chunk (8 cin each).
// W2b: [e][grp][512 chunks][8], chunk pos p = co*4 + ((c + co + (co>>2)) & 3),
//   c = ch chunk within the 32-ch group.
// The rotations make the kernel's strided ds_read_b128 patterns conflict-free.
__global__ __launch_bounds__(256) void convert_w_kernel(
    const float* __restrict__ W1, const float* __restrict__ W2,
    unsigned short* __restrict__ W1b, unsigned short* __restrict__ W2b) {
  const int i   = blockIdx.x * 256 + threadIdx.x;   // 0 .. 262143
  const int j   = i & 7;
  const int p   = (i >> 3) & 511;
  const int grp = (i >> 12) & 7;
  const int e   = i >> 15;
  {
    const int r   = p >> 4;
    const int c   = ((p & 15) - r) & 15;
    const int row = r & 15, mt = r >> 4;
    const int ch  = grp * 32 + ((row >> 2) << 3) + (row & 3) + (mt << 2);
    W1b[i] = f2bf(W1[(e * CHID + ch) * CIN + c * 8 + j]);
  }
  {
    const int co = p >> 2;
    const int c  = ((p & 3) - co - (co >> 2)) & 3;
    const int ch = grp * 32 + c * 8 + j;
    W2b[i] = f2bf(W2[(e * COUT + co) * CHID + ch]);
  }
}

__global__ __launch_bounds__(256, 2) void moe_kernel(
    const float* __restrict__ x, const float* __restrict__ wts,
    const int* __restrict__ idx, const unsigned short* __restrict__ W1,
    const float* __restrict__ b1, const unsigned short* __restrict__ W2,
    const float* __restrict__ b2, float* __restrict__ out) {
  // 80 KB total -> exactly 2 blocks/CU on 160 KB LDS.
  // [0,32768): x tiles, 4 waves x 16 KB (swizzled chunks)
  // [32768,36864): W1 slice (8 KB)   [36864,40960): W2 slice (8 KB)
  __shared__ __align__(16) unsigned short lds[40960];

  const int tid  = threadIdx.x;
  const int wave = tid >> 6;
  const int lane = tid & 63;
  const int q    = lane >> 4;
  const int r16  = lane & 15;

  const int  b     = blockIdx.x / 7;
  const int  t4    = blockIdx.x % 7;
  const int  tile  = t4 * 4 + wave;          // 0..27 (25..27 idle)
  const bool valid = (tile < 25);
  const int  tileC = valid ? tile : 24;      // clamp for safe addressing
  const int  px0   = tileC * 64;

  unsigned short* xw = &lds[wave * 8192];    // this wave's 16 KB x region

  // ---- stage x tile (within-wave producer/consumer -> no barrier needed)
  {
    const float* xb = x + (long)b * CIN * HWPX + px0 + lane;
#pragma unroll 4
    for (int c = 0; c < 16; ++c) {
      float v[8];
#pragma unroll
      for (int jj = 0; jj < 8; ++jj) v[jj] = xb[(long)(c * 8 + jj) * HWPX];
      union { bf16x8 w; unsigned int u[4]; } t;
#pragma unroll
      for (int d = 0; d < 4; ++d) t.u[d] = pack_bf2(v[2 * d], v[2 * d + 1]);
      const int slot = (c + lane) & 15;      // rotation swizzle
      *reinterpret_cast<bf16x8*>(&xw[(lane * 16 + slot) * 8]) = t.w;
    }
  }

  const int   e0 = idx[b * 2 + 0], e1 = idx[b * 2 + 1];
  const float g0 = wts[b * 2 + 0], g1 = wts[b * 2 + 1];

  f32x4 accO[8][4];
#pragma unroll
  for (int mt = 0; mt < 8; ++mt)
#pragma unroll
    for (int nt = 0; nt < 4; ++nt) accO[mt][nt] = (f32x4){0.f, 0.f, 0.f, 0.f};

  const uint4* w1g = reinterpret_cast<const uint4*>(W1);
  const uint4* w2g = reinterpret_cast<const uint4*>(W2);
  uint4* ws1 = reinterpret_cast<uint4*>(&lds[32768]);
  uint4* ws2 = reinterpret_cast<uint4*>(&lds[36864]);

  // preload slices for gs=0 into registers
  uint4 p1a, p1b, p2a, p2b;
  {
    const long base = (long)e0 * 4096 + tid;   // (e*8+grp)*512 + tid, grp=0
    p1a = w1g[base]; p1b = w1g[base + 256];
    p2a = w2g[base]; p2b = w2g[base + 256];
  }

  for (int gs = 0; gs < 16; ++gs) {
    const int   slot = gs >> 3;
    const int   grp  = gs & 7;
    const int   e    = slot ? e1 : e0;
    const float g    = slot ? g1 : g0;

    __syncthreads();                         // prior group done reading ws*
    ws1[tid] = p1a; ws1[tid + 256] = p1b;
    ws2[tid] = p2a; ws2[tid + 256] = p2b;
    __syncthreads();                         // slice gs visible

    if (gs < 15) {                           // prefetch next slice (hidden by compute)
      const int  gs2  = gs + 1;
      const int  e2   = (gs2 >> 3) ? e1 : e0;
      const long base = (long)e2 * 4096 + (long)(gs2 & 7) * 512 + tid;
      p1a = w1g[base]; p1b = w1g[base + 256];
      p2a = w2g[base]; p2b = w2g[base + 256];
    }

    // ---- GEMM1: 32 hidden ch (permuted rows), K = 128
    f32x4 aA[4], aB[4];
#pragma unroll
    for (int nt = 0; nt < 4; ++nt) {
      aA[nt] = (f32x4){0.f, 0.f, 0.f, 0.f};
      aB[nt] = (f32x4){0.f, 0.f, 0.f, 0.f};
    }
#pragma unroll
    for (int ks = 0; ks < 4; ++ks) {
      const int slotw = (ks * 4 + q + r16) & 15;   // same rotation for R0/R0+16
      const bf16x8 w0 = *reinterpret_cast<const bf16x8*>(
          &lds[32768 + (r16 * 16 + slotw) * 8]);
      const bf16x8 w1v = *reinterpret_cast<const bf16x8*>(
          &lds[32768 + ((r16 + 16) * 16 + slotw) * 8]);
#pragma unroll
      for (int nt = 0; nt < 4; ++nt) {
        const int px = nt * 16 + r16;
        const bf16x8 xf = *reinterpret_cast<const bf16x8*>(
            &xw[(px * 16 + ((ks * 4 + q + px) & 15)) * 8]);
        aA[nt] = __builtin_amdgcn_mfma_f32_16x16x32_bf16(w0, xf, aA[nt], 0, 0, 0);
        aB[nt] = __builtin_amdgcn_mfma_f32_16x16x32_bf16(w1v, xf, aB[nt], 0, 0, 0);
      }
    }

    // ---- bias + SiLU + gate -> GEMM2 B-fragments (true ch = base + q*8 + j)
    const float* b1e = b1 + e * CHID + grp * 32;
    const f32x4 bA = *reinterpret_cast<const f32x4*>(&b1e[q * 8]);
    const f32x4 bB = *reinterpret_cast<const f32x4*>(&b1e[q * 8 + 4]);
    union { bf16x8 v; unsigned int u[4]; } h[4];
#pragma unroll
    for (int nt = 0; nt < 4; ++nt) {
      h[nt].u[0] = silu_gate_pk(aA[nt][0] + bA[0], aA[nt][1] + bA[1], g);
      h[nt].u[1] = silu_gate_pk(aA[nt][2] + bA[2], aA[nt][3] + bA[3], g);
      h[nt].u[2] = silu_gate_pk(aB[nt][0] + bB[0], aB[nt][1] + bB[1], g);
      h[nt].u[3] = silu_gate_pk(aB[nt][2] + bB[2], aB[nt][3] + bB[3], g);
    }

    // ---- GEMM2 partial-K (this 32-ch chunk)
#pragma unroll
    for (int mt = 0; mt < 8; ++mt) {
      const int co = mt * 16 + r16;
      const bf16x8 w2v = *reinterpret_cast<const bf16x8*>(
          &lds[36864 + (co * 4 + ((q + co + (co >> 2)) & 3)) * 8]);
#pragma unroll
      for (int nt = 0; nt < 4; ++nt)
        accO[mt][nt] = __builtin_amdgcn_mfma_f32_16x16x32_bf16(w2v, h[nt].v, accO[mt][nt], 0, 0, 0);
    }
  }

  // ---- epilogue: per-wave LDS transpose (reuse dead x region; DS FIFO
  //      ordering within a wave -> no barriers), coalesced 16 B stores.
  float* eb = reinterpret_cast<float*>(xw);  // [16][68] f32 = 4352 B <= 16 KB
  const float* b2e0 = b2 + e0 * COUT;
  const float* b2e1 = b2 + e1 * COUT;
  const int  coR   = lane >> 2;              // 0..15
  const int  qtr   = lane & 3;
  const long orow0 = (long)b * COUT * HWPX + px0 + qtr * 16;
#pragma unroll
  for (int mt = 0; mt < 8; ++mt) {
    const int coW = q * 4;
    const f32x4 bias = g0 * (*reinterpret_cast<const f32x4*>(&b2e0[mt * 16 + coW])) +
                       g1 * (*reinterpret_cast<const f32x4*>(&b2e1[mt * 16 + coW]));
#pragma unroll
    for (int nt = 0; nt < 4; ++nt) {
      const f32x4 v = accO[mt][nt] + bias;
#pragma unroll
      for (int rr = 0; rr < 4; ++rr)
        eb[(coW + rr) * 68 + nt * 16 + r16] = v[rr];
    }
    if (valid) {
      const long orow = orow0 + (long)(mt * 16 + coR) * HWPX;
#pragma unroll
      for (int i4 = 0; i4 < 4; ++i4) {
        const float4 ov = *reinterpret_cast<const float4*>(
            &eb[coR * 68 + qtr * 16 + i4 * 4]);
        *reinterpret_cast<float4*>(&out[orow + i4 * 4]) = ov;
      }
    }
  }
}

extern "C" void kernel_launch(void* const* d_in, const int* in_sizes, int n_in,
                              void* d_out, int out_size, void* d_ws, size_t ws_size,
                              hipStream_t stream) {
  const float* x   = (const float*)d_in[0];
  const float* wts = (const float*)d_in[1];
  const int*   idx = (const int*)d_in[2];
  const float* W1  = (const float*)d_in[3];
  const float* b1  = (const float*)d_in[4];
  const float* W2  = (const float*)d_in[5];
  const float* b2  = (const float*)d_in[6];
  float* out = (float*)d_out;

  unsigned short* W1b = (unsigned short*)d_ws;                    // 8*8*512*8
  unsigned short* W2b = (unsigned short*)d_ws + (8 * CHID * CIN); // same size

  convert_w_kernel<<<262144 / 256, 256, 0, stream>>>(W1, W2, W1b, W2b);
  moe_kernel<<<128 * 7, 256, 0, stream>>>(x, wts, idx, W1b, b1, W2b, b2, out);
}